// Round 13
// baseline (114.915 us; speedup 1.0000x reference)
//
#include <hip/hip_runtime.h>

#define SEQ 2048
#define FR  133        // frame repr len
#define H0I 3
#define H1I 68
#define NOHAND -1.0f

#define CH_FRAMES 256                  // frames per chunk (stream kernel)
#define CH_ELEMS  (CH_FRAMES * FR)     // 34048 floats
#define CH_VEC    (CH_ELEMS / 4)       // 8512 float4 (exact)
#define NCHUNK    (SEQ / CH_FRAMES)    // 8
#define DEPTH     8                    // independent loads per batch
#define CH_MAIN   ((CH_VEC / (DEPTH * 256)) * (DEPTH * 256))  // 8192
#define TW        140                  // table width: 133 + 7 wrap slots

typedef float f32x4 __attribute__((ext_vector_type(4)));

// ---- Kernel 1: per-sequence reference wrists via backward early-exit scan ----
__global__ __launch_bounds__(64) void refs_kernel(
    const float* __restrict__ X, float* __restrict__ refs /*[B][8]*/) {
    const int b    = blockIdx.x;
    const int lane = threadIdx.x;            // one wave
    const float* xb = X + (size_t)b * (SEQ * FR);

    int last0 = -1, last1 = -1;
    for (int start = SEQ - 64; ; start -= 64) {
        int t = start + lane;
        float v0 = xb[(size_t)t * FR + H0I];
        float v1 = xb[(size_t)t * FR + H1I];
        unsigned long long b0 = __ballot(v0 != NOHAND);
        unsigned long long b1 = __ballot(v1 != NOHAND);
        if (last0 < 0 && b0) last0 = start + 63 - __builtin_clzll(b0);
        if (last1 < 0 && b1) last1 = start + 63 - __builtin_clzll(b1);
        if ((last0 >= 0 && last1 >= 0) || start == 0) break;
    }
    if (lane == 0) {
        int l0 = last0 < 0 ? 0 : last0;      // jnp.maximum(..., 0)
        int l1 = last1 < 0 ? 0 : last1;
        float* r = refs + b * 8;
        r[0] = xb[(size_t)l0 * FR + 5];
        r[1] = xb[(size_t)l0 * FR + 26];
        r[2] = xb[(size_t)l0 * FR + 47];
        r[3] = xb[(size_t)l1 * FR + 70];
        r[4] = xb[(size_t)l1 * FR + 91];
        r[5] = xb[(size_t)l1 * FR + 112];
    }
}

__device__ __forceinline__ float subval(int f, int mk,
    float r0x, float r0y, float r0z, float r1x, float r1y, float r1z) {
    float s0 = (f >= 47) ? r0z : ((f >= 26) ? r0y : r0x);
    float s1 = (f >= 112) ? r1z : ((f >= 91) ? r1y : r1x);
    bool h0 = (f >= 5) & (f < 68) & ((mk & 1) != 0);
    bool h1 = (f >= 70) & ((mk & 2) != 0);
    return h0 ? s0 : (h1 ? s1 : 0.0f);
}

// ---- Kernel 2: stream with precomputed LDS subtrahend table ----
__global__ __launch_bounds__(256) void stream_kernel(
    const float* __restrict__ X, float* __restrict__ Out,
    const float* __restrict__ refs) {
    __shared__ unsigned char s_mask[CH_FRAMES + 1];  // +1 sentinel
    __shared__ unsigned char s_pair[CH_FRAMES];      // mk[f]<<2 | mk[f+1]
    __shared__ float s_T[16 * TW];                   // subtrahend per (pair, f)
    __shared__ float s_ref[6];

    const int blk = blockIdx.x;
    const int seq = blk >> 3;                // / NCHUNK
    const int ch  = blk & (NCHUNK - 1);
    const int tid = threadIdx.x;

    const float* xb = X   + (size_t)seq * (SEQ * FR) + (size_t)ch * CH_ELEMS;
    float*       ob = Out + (size_t)seq * (SEQ * FR) + (size_t)ch * CH_ELEMS;

    // mask stage: 1 frame per thread (also prefetches this block's own lines)
    {
        float v0 = xb[(size_t)tid * FR + H0I];
        float v1 = xb[(size_t)tid * FR + H1I];
        s_mask[tid] = (unsigned char)((v0 != NOHAND) | ((v1 != NOHAND) << 1));
    }
    if (tid == 0) s_mask[CH_FRAMES] = 0;     // sentinel (never selected by math)
    if (tid < 6) s_ref[tid] = refs[seq * 8 + tid];
    __syncthreads();

    // build the (mask-pair, column) subtrahend table + per-frame pair index
    {
        const float r0x = s_ref[0], r0y = s_ref[1], r0z = s_ref[2];
        const float r1x = s_ref[3], r1y = s_ref[4], r1z = s_ref[5];
        for (int idx = tid; idx < 16 * TW; idx += 256) {
            int p = idx / TW, f = idx - p * TW;
            float val = (f < FR)
                ? subval(f,      p >> 2, r0x, r0y, r0z, r1x, r1y, r1z)
                : subval(f - FR, p & 3,  r0x, r0y, r0z, r1x, r1y, r1z);
            s_T[idx] = val;
        }
        s_pair[tid] = (unsigned char)((s_mask[tid] << 2) | s_mask[tid + 1]);
    }
    __syncthreads();

    const f32x4* xv = (const f32x4*)xb;
    f32x4*       ov = (f32x4*)ob;

    auto process = [&](f32x4& v, int i) {
        int e     = i * 4;
        int frame = (int)((unsigned)e / 133u);   // magic-mul div
        int f0    = e - frame * 133;
        int base  = (int)s_pair[frame] * TW + f0;
        #pragma unroll
        for (int j = 0; j < 4; ++j) v[j] -= s_T[base + j];
    };

    // main body: DEPTH independent 16B nt-loads in flight per batch
    for (int base = tid; base + (DEPTH - 1) * 256 < CH_VEC; base += DEPTH * 256) {
        f32x4 v[DEPTH];
        #pragma unroll
        for (int u = 0; u < DEPTH; ++u)
            v[u] = __builtin_nontemporal_load(&xv[base + u * 256]);
        #pragma unroll
        for (int u = 0; u < DEPTH; ++u) {
            int i = base + u * 256;
            process(v[u], i);
            __builtin_nontemporal_store(v[u], &ov[i]);
        }
    }
    // tail: remaining 320 vectors
    for (int i = CH_MAIN + tid; i < CH_VEC; i += 256) {
        f32x4 v = __builtin_nontemporal_load(&xv[i]);
        process(v, i);
        __builtin_nontemporal_store(v, &ov[i]);
    }
}

extern "C" void kernel_launch(void* const* d_in, const int* in_sizes, int n_in,
                              void* d_out, int out_size, void* d_ws, size_t ws_size,
                              hipStream_t stream) {
    const float* X = (const float*)d_in[0];
    float* Out     = (float*)d_out;
    float* refs    = (float*)d_ws;               // [B][8] = 8 KB
    int nB = in_sizes[0] / (SEQ * FR);           // 256
    refs_kernel<<<nB, 64, 0, stream>>>(X, refs);
    stream_kernel<<<nB * NCHUNK, 256, 0, stream>>>(X, Out, refs);
}

// Round 14
// 111.962 us; speedup vs baseline: 1.0264x; 1.0264x over previous
//
#include <hip/hip_runtime.h>

#define SEQ 2048
#define FR  133        // frame repr len
#define H0I 3
#define H1I 68
#define NOHAND -1.0f

#define CH_FRAMES 256                  // frames per chunk (stream kernel)
#define CH_ELEMS  (CH_FRAMES * FR)     // 34048 floats
#define CH_VEC    (CH_ELEMS / 4)       // 8512 float4 (exact)
#define NCHUNK    (SEQ / CH_FRAMES)    // 8
#define DEPTH     4                    // independent loads per batch (measured optimum)
#define CH_MAIN   ((CH_VEC / (DEPTH * 256)) * (DEPTH * 256))  // 8192
#define TW        140                  // table width: 133 + 7 wrap slots

typedef float f32x4 __attribute__((ext_vector_type(4)));

// ---- Kernel 1: per-sequence reference wrists via backward early-exit scan ----
__global__ __launch_bounds__(64) void refs_kernel(
    const float* __restrict__ X, float* __restrict__ refs /*[B][8]*/) {
    const int b    = blockIdx.x;
    const int lane = threadIdx.x;            // one wave
    const float* xb = X + (size_t)b * (SEQ * FR);

    int last0 = -1, last1 = -1;
    for (int start = SEQ - 64; ; start -= 64) {
        int t = start + lane;
        float v0 = xb[(size_t)t * FR + H0I];
        float v1 = xb[(size_t)t * FR + H1I];
        unsigned long long b0 = __ballot(v0 != NOHAND);
        unsigned long long b1 = __ballot(v1 != NOHAND);
        if (last0 < 0 && b0) last0 = start + 63 - __builtin_clzll(b0);
        if (last1 < 0 && b1) last1 = start + 63 - __builtin_clzll(b1);
        if ((last0 >= 0 && last1 >= 0) || start == 0) break;
    }
    if (lane == 0) {
        int l0 = last0 < 0 ? 0 : last0;      // jnp.maximum(..., 0)
        int l1 = last1 < 0 ? 0 : last1;
        float* r = refs + b * 8;
        r[0] = xb[(size_t)l0 * FR + 5];
        r[1] = xb[(size_t)l0 * FR + 26];
        r[2] = xb[(size_t)l0 * FR + 47];
        r[3] = xb[(size_t)l1 * FR + 70];
        r[4] = xb[(size_t)l1 * FR + 91];
        r[5] = xb[(size_t)l1 * FR + 112];
    }
}

__device__ __forceinline__ float subval(int f, int mk,
    float r0x, float r0y, float r0z, float r1x, float r1y, float r1z) {
    float s0 = (f >= 47) ? r0z : ((f >= 26) ? r0y : r0x);
    float s1 = (f >= 112) ? r1z : ((f >= 91) ? r1y : r1x);
    bool h0 = (f >= 5) & (f < 68) & ((mk & 1) != 0);
    bool h1 = (f >= 70) & ((mk & 2) != 0);
    return h0 ? s0 : (h1 ? s1 : 0.0f);
}

// ---- Kernel 2: stream with precomputed LDS subtrahend table ----
__global__ __launch_bounds__(256) void stream_kernel(
    const float* __restrict__ X, float* __restrict__ Out,
    const float* __restrict__ refs) {
    __shared__ unsigned char s_mask[CH_FRAMES + 1];  // +1 sentinel
    __shared__ unsigned char s_pair[CH_FRAMES];      // mk[f]<<2 | mk[f+1]
    __shared__ float s_T[16 * TW];                   // subtrahend per (pair, f)
    __shared__ float s_ref[6];

    const int blk = blockIdx.x;
    const int seq = blk >> 3;                // / NCHUNK
    const int ch  = blk & (NCHUNK - 1);
    const int tid = threadIdx.x;

    const float* xb = X   + (size_t)seq * (SEQ * FR) + (size_t)ch * CH_ELEMS;
    float*       ob = Out + (size_t)seq * (SEQ * FR) + (size_t)ch * CH_ELEMS;

    // mask stage: 1 frame per thread (also prefetches this block's own lines)
    {
        float v0 = xb[(size_t)tid * FR + H0I];
        float v1 = xb[(size_t)tid * FR + H1I];
        s_mask[tid] = (unsigned char)((v0 != NOHAND) | ((v1 != NOHAND) << 1));
    }
    if (tid == 0) s_mask[CH_FRAMES] = 0;     // sentinel (never selected by math)
    if (tid < 6) s_ref[tid] = refs[seq * 8 + tid];
    __syncthreads();

    // build the (mask-pair, column) subtrahend table + per-frame pair index
    {
        const float r0x = s_ref[0], r0y = s_ref[1], r0z = s_ref[2];
        const float r1x = s_ref[3], r1y = s_ref[4], r1z = s_ref[5];
        for (int idx = tid; idx < 16 * TW; idx += 256) {
            int p = idx / TW, f = idx - p * TW;
            float val = (f < FR)
                ? subval(f,      p >> 2, r0x, r0y, r0z, r1x, r1y, r1z)
                : subval(f - FR, p & 3,  r0x, r0y, r0z, r1x, r1y, r1z);
            s_T[idx] = val;
        }
        s_pair[tid] = (unsigned char)((s_mask[tid] << 2) | s_mask[tid + 1]);
    }
    __syncthreads();

    const f32x4* xv = (const f32x4*)xb;
    f32x4*       ov = (f32x4*)ob;

    auto process = [&](f32x4& v, int i) {
        int e     = i * 4;
        int frame = (int)((unsigned)e / 133u);   // magic-mul div
        int f0    = e - frame * 133;
        int base  = (int)s_pair[frame] * TW + f0;
        #pragma unroll
        for (int j = 0; j < 4; ++j) v[j] -= s_T[base + j];
    };

    // main body: DEPTH independent 16B nt-loads in flight per batch
    for (int base = tid; base + (DEPTH - 1) * 256 < CH_VEC; base += DEPTH * 256) {
        f32x4 v[DEPTH];
        #pragma unroll
        for (int u = 0; u < DEPTH; ++u)
            v[u] = __builtin_nontemporal_load(&xv[base + u * 256]);
        #pragma unroll
        for (int u = 0; u < DEPTH; ++u) {
            int i = base + u * 256;
            process(v[u], i);
            __builtin_nontemporal_store(v[u], &ov[i]);
        }
    }
    // tail: remaining 320 vectors
    for (int i = CH_MAIN + tid; i < CH_VEC; i += 256) {
        f32x4 v = __builtin_nontemporal_load(&xv[i]);
        process(v, i);
        __builtin_nontemporal_store(v, &ov[i]);
    }
}

extern "C" void kernel_launch(void* const* d_in, const int* in_sizes, int n_in,
                              void* d_out, int out_size, void* d_ws, size_t ws_size,
                              hipStream_t stream) {
    const float* X = (const float*)d_in[0];
    float* Out     = (float*)d_out;
    float* refs    = (float*)d_ws;               // [B][8] = 8 KB
    int nB = in_sizes[0] / (SEQ * FR);           // 256
    refs_kernel<<<nB, 64, 0, stream>>>(X, refs);
    stream_kernel<<<nB * NCHUNK, 256, 0, stream>>>(X, Out, refs);
}